// Round 5
// baseline (40.691 us; speedup 1.0000x reference)
//
#include <hip/hip_runtime.h>
#include <hip/hip_bf16.h>

#define BLOCK 256
#define PER_THREAD 4   // pairs per thread, all loads issued up front

__device__ __forceinline__ float frcp(float x) { return __builtin_amdgcn_rcpf(x); }
__device__ __forceinline__ float fsqrt(float x) { return __builtin_amdgcn_sqrtf(x); }

// fast acos: Abramowitz-Stegun 4.4.45, abs err ~6.7e-5 rad
__device__ __forceinline__ float facos(float x) {
    float ax = fabsf(x);
    float sq = fsqrt(fmaxf(1.0f - ax, 0.0f));
    float poly = fmaf(fmaf(fmaf(-0.0187293f, ax, 0.0742610f), ax, -0.2121144f),
                      ax, 1.5707288f);
    float ac = sq * poly;
    return (x < 0.0f) ? (3.14159274f - ac) : ac;
}

// logm of a symmetric 3x3 SPD matrix, output as 6 unique entries
// L = {L00, L01, L02, L11, L12, L22}
__device__ __forceinline__ void logm3(const float m[6], float L[6]) {
    float a00 = m[0], a01 = m[1], a02 = m[2];
    float a11 = m[3], a12 = m[4], a22 = m[5];

    float q  = (a00 + a11 + a22) * (1.0f / 3.0f);
    float b00 = a00 - q, b11 = a11 - q, b22 = a22 - q;
    float p2 = b00*b00 + b11*b11 + b22*b22
             + 2.0f * (a01*a01 + a02*a02 + a12*a12);
    float p  = fsqrt(p2 * (1.0f / 6.0f));
    p = fmaxf(p, 1e-12f);
    float ip = frcp(p);
    float detB = b00*(b11*b22 - a12*a12)
               - a01*(a01*b22 - a12*a02)
               + a02*(a01*a12 - b11*a02);
    float ip3 = ip * ip * ip;
    float r = fminf(fmaxf(0.5f * detB * ip3, -1.0f), 1.0f);
    float phi = facos(r) * (1.0f / 3.0f);
    float sph = __sinf(phi), cph = __cosf(phi);
    float whi = q + 2.0f * p * cph;
    float wlo = q - p * (cph + 1.7320508f * sph);
    float wmid = 3.0f * q - whi - wlo;
    float w0 = fmaxf(wlo,  1e-8f);
    float w1 = fmaxf(wmid, 1e-8f);
    float w2 = fmaxf(whi,  1e-8f);

    float l0 = __logf(w0), l1 = __logf(w1), l2 = __logf(w2);
    float d01 = w1 - w0, d12 = w2 - w1, span = w2 - w0;
    float thr = 1e-3f * w1;
    float dd01 = (d01 > thr) ? (l1 - l0) * frcp(d01) : 2.0f * frcp(w0 + w1);
    float dd12 = (d12 > thr) ? (l2 - l1) * frcp(d12) : 2.0f * frcp(w1 + w2);
    float dd012 = (span > thr) ? (dd12 - dd01) * frcp(span)
                               : -0.5f * frcp(w1 * w1);
    float k2 = dd012;
    float k1 = dd01 - dd012 * (w0 + w1);
    float k0 = l0 - dd01 * w0 + dd012 * (w0 * w1);

    float s00 = a00*a00 + a01*a01 + a02*a02;
    float s01 = a00*a01 + a01*a11 + a02*a12;
    float s02 = a00*a02 + a01*a12 + a02*a22;
    float s11 = a01*a01 + a11*a11 + a12*a12;
    float s12 = a01*a02 + a11*a12 + a12*a22;
    float s22 = a02*a02 + a12*a12 + a22*a22;

    L[0] = k0 + k1*a00 + k2*s00;
    L[1] =      k1*a01 + k2*s01;
    L[2] =      k1*a02 + k2*s02;
    L[3] = k0 + k1*a11 + k2*s11;
    L[4] =      k1*a12 + k2*s12;
    L[5] = k0 + k1*a22 + k2*s22;
}

__device__ __forceinline__ void load6(const float* __restrict__ a, float m[6]) {
    m[0] = a[0]; m[1] = a[1]; m[2] = a[2];
    m[3] = a[4]; m[4] = a[5]; m[5] = a[8];
}

__device__ __forceinline__ float fnorm2_diff(const float L1[6], const float L2[6]) {
    float d0 = L1[0]-L2[0], d1 = L1[1]-L2[1], d2 = L1[2]-L2[2];
    float d3 = L1[3]-L2[3], d4 = L1[4]-L2[4], d5 = L1[5]-L2[5];
    return d0*d0 + d3*d3 + d5*d5 + 2.0f * (d1*d1 + d2*d2 + d4*d4);
}

__global__ void __launch_bounds__(BLOCK)
le_partial(const float* __restrict__ D1, const float* __restrict__ D2,
           float* __restrict__ partial, int n) {
    const int tid = threadIdx.x;
    const long S = (long)gridDim.x * BLOCK;   // stride between a thread's pairs
    const long i0 = (long)blockIdx.x * BLOCK + tid;

    // ---- issue ALL loads up front: 4 pairs x 12 floats = 48 registers ----
    float a1[PER_THREAD][6], a2[PER_THREAD][6];
    bool hv[PER_THREAD];
    #pragma unroll
    for (int k = 0; k < PER_THREAD; ++k) {
        long idx = i0 + (long)k * S;
        hv[k] = (idx < n);
        if (hv[k]) {
            load6(D1 + idx * 9, a1[k]);
            load6(D2 + idx * 9, a2[k]);
        }
    }
    // Pin the load cluster above the compute: scheduler may not sink loads
    // past this point (prevents the round-4 failure where the compiler
    // rescheduled "prefetch" loads next to their uses to save registers).
    __builtin_amdgcn_sched_barrier(0);

    // ---- compute; remaining loads stay in flight under the VALU work ----
    float acc = 0.0f;
    #pragma unroll
    for (int k = 0; k < PER_THREAD; ++k) {
        if (hv[k]) {
            float L1[6], L2[6];
            logm3(a1[k], L1);
            logm3(a2[k], L2);
            acc += fnorm2_diff(L1, L2);
        }
    }

    // wave reduce (wave = 64)
    #pragma unroll
    for (int off = 32; off > 0; off >>= 1)
        acc += __shfl_down(acc, off, 64);
    __shared__ float wsum[BLOCK / 64];
    if ((tid & 63) == 0) wsum[tid >> 6] = acc;
    __syncthreads();
    if (tid == 0) {
        float s = 0.0f;
        #pragma unroll
        for (int j = 0; j < BLOCK / 64; ++j) s += wsum[j];
        partial[blockIdx.x] = s;
    }
}

__global__ void __launch_bounds__(BLOCK)
le_final(const float* __restrict__ partial, int nparts,
         float* __restrict__ out, double invN) {
    double s = 0.0;
    for (int i = threadIdx.x; i < nparts; i += BLOCK)
        s += (double)partial[i];
    #pragma unroll
    for (int off = 32; off > 0; off >>= 1)
        s += __shfl_down(s, off, 64);
    __shared__ double ws[BLOCK / 64];
    if ((threadIdx.x & 63) == 0) ws[threadIdx.x >> 6] = s;
    __syncthreads();
    if (threadIdx.x == 0) {
        double t = 0.0;
        #pragma unroll
        for (int i = 0; i < BLOCK / 64; ++i) t += ws[i];
        out[0] = (float)(t * invN);
    }
}

extern "C" void kernel_launch(void* const* d_in, const int* in_sizes, int n_in,
                              void* d_out, int out_size, void* d_ws, size_t ws_size,
                              hipStream_t stream) {
    const float* D1 = (const float*)d_in[0];
    const float* D2 = (const float*)d_in[1];
    float* out = (float*)d_out;
    float* partial = (float*)d_ws;

    int n = in_sizes[0] / 9;
    int grid = (n + BLOCK * PER_THREAD - 1) / (BLOCK * PER_THREAD);
    int maxblocks = (int)(ws_size / sizeof(float));
    if (maxblocks > 0 && grid > maxblocks) grid = maxblocks;
    if (grid < 1) grid = 1;

    le_partial<<<grid, BLOCK, 0, stream>>>(D1, D2, partial, n);
    le_final<<<1, BLOCK, 0, stream>>>(partial, grid, out, 1.0 / (double)n);
}

// Round 6
// 33.237 us; speedup vs baseline: 1.2243x; 1.2243x over previous
//
#include <hip/hip_runtime.h>
#include <hip/hip_bf16.h>

#define BLOCK 256
#define TILE 256                    // pairs per tile (== BLOCK)
#define TILE_FLOATS (TILE * 9)      // 2304 floats per input per tile
#define CHUNKS 18                   // 18 x 1024B DMA chunks cover D1+D2 tile

__device__ __forceinline__ float frcp(float x) { return __builtin_amdgcn_rcpf(x); }
__device__ __forceinline__ float fsqrt(float x) { return __builtin_amdgcn_sqrtf(x); }

// fast acos: Abramowitz-Stegun 4.4.45, abs err ~6.7e-5 rad
__device__ __forceinline__ float facos(float x) {
    float ax = fabsf(x);
    float sq = fsqrt(fmaxf(1.0f - ax, 0.0f));
    float poly = fmaf(fmaf(fmaf(-0.0187293f, ax, 0.0742610f), ax, -0.2121144f),
                      ax, 1.5707288f);
    float ac = sq * poly;
    return (x < 0.0f) ? (3.14159274f - ac) : ac;
}

// logm of a symmetric 3x3 SPD matrix, 6 unique entries {00,01,02,11,12,22}
__device__ __forceinline__ void logm3(const float m[6], float L[6]) {
    float a00 = m[0], a01 = m[1], a02 = m[2];
    float a11 = m[3], a12 = m[4], a22 = m[5];

    float q  = (a00 + a11 + a22) * (1.0f / 3.0f);
    float b00 = a00 - q, b11 = a11 - q, b22 = a22 - q;
    float p2 = b00*b00 + b11*b11 + b22*b22
             + 2.0f * (a01*a01 + a02*a02 + a12*a12);
    float p  = fsqrt(p2 * (1.0f / 6.0f));
    p = fmaxf(p, 1e-12f);
    float ip = frcp(p);
    float detB = b00*(b11*b22 - a12*a12)
               - a01*(a01*b22 - a12*a02)
               + a02*(a01*a12 - b11*a02);
    float ip3 = ip * ip * ip;
    float r = fminf(fmaxf(0.5f * detB * ip3, -1.0f), 1.0f);
    float phi = facos(r) * (1.0f / 3.0f);
    float sph = __sinf(phi), cph = __cosf(phi);
    float whi = q + 2.0f * p * cph;
    float wlo = q - p * (cph + 1.7320508f * sph);
    float wmid = 3.0f * q - whi - wlo;
    float w0 = fmaxf(wlo,  1e-8f);
    float w1 = fmaxf(wmid, 1e-8f);
    float w2 = fmaxf(whi,  1e-8f);

    float l0 = __logf(w0), l1 = __logf(w1), l2 = __logf(w2);
    float d01 = w1 - w0, d12 = w2 - w1, span = w2 - w0;
    float thr = 1e-3f * w1;
    float dd01 = (d01 > thr) ? (l1 - l0) * frcp(d01) : 2.0f * frcp(w0 + w1);
    float dd12 = (d12 > thr) ? (l2 - l1) * frcp(d12) : 2.0f * frcp(w1 + w2);
    float dd012 = (span > thr) ? (dd12 - dd01) * frcp(span)
                               : -0.5f * frcp(w1 * w1);
    float k2 = dd012;
    float k1 = dd01 - dd012 * (w0 + w1);
    float k0 = l0 - dd01 * w0 + dd012 * (w0 * w1);

    float s00 = a00*a00 + a01*a01 + a02*a02;
    float s01 = a00*a01 + a01*a11 + a02*a12;
    float s02 = a00*a02 + a01*a12 + a02*a22;
    float s11 = a01*a01 + a11*a11 + a12*a12;
    float s12 = a01*a02 + a11*a12 + a12*a22;
    float s22 = a02*a02 + a12*a12 + a22*a22;

    L[0] = k0 + k1*a00 + k2*s00;
    L[1] =      k1*a01 + k2*s01;
    L[2] =      k1*a02 + k2*s02;
    L[3] = k0 + k1*a11 + k2*s11;
    L[4] =      k1*a12 + k2*s12;
    L[5] = k0 + k1*a22 + k2*s22;
}

__device__ __forceinline__ void load6(const float* __restrict__ a, float m[6]) {
    m[0] = a[0]; m[1] = a[1]; m[2] = a[2];
    m[3] = a[4]; m[4] = a[5]; m[5] = a[8];
}

__device__ __forceinline__ float fnorm2_diff(const float L1[6], const float L2[6]) {
    float d0 = L1[0]-L2[0], d1 = L1[1]-L2[1], d2 = L1[2]-L2[2];
    float d3 = L1[3]-L2[3], d4 = L1[4]-L2[4], d5 = L1[5]-L2[5];
    return d0*d0 + d3*d3 + d5*d5 + 2.0f * (d1*d1 + d2*d2 + d4*d4);
}

// Async DMA one tile (D1 then D2, 18 KiB) into LDS buffer `buf`.
// Chunk c = 1024 B = 64 lanes x 16 B; wave w takes chunks w, w+4, ...
// LDS dest is wave-uniform base; HW adds lane*16 (global src matches).
__device__ __forceinline__ void issue_tile(float* buf,
                                           const float* __restrict__ D1,
                                           const float* __restrict__ D2,
                                           long t, int wave, int lane) {
    const float* s1 = D1 + t * TILE_FLOATS;
    const float* s2 = D2 + t * TILE_FLOATS;
    #pragma unroll
    for (int k = 0; k < 5; ++k) {
        int c = wave + k * 4;
        if (c < CHUNKS) {
            const float* g = (c < 9 ? s1 + c * 256 : s2 + (c - 9) * 256) + lane * 4;
            float* l = buf + c * 256;
            __builtin_amdgcn_global_load_lds(
                (const __attribute__((address_space(1))) unsigned int*)g,
                (__attribute__((address_space(3))) unsigned int*)l,
                16, 0, 0);
        }
    }
}

__global__ void __launch_bounds__(BLOCK)
le_partial(const float* __restrict__ D1, const float* __restrict__ D2,
           float* __restrict__ partial, int n, int ntiles) {
    __shared__ __align__(16) float lds[2 * 2 * TILE_FLOATS];  // 2 bufs x (D1|D2)
    const int tid  = threadIdx.x;
    const int wave = tid >> 6, lane = tid & 63;
    const int tstep = gridDim.x;
    float acc = 0.0f;

    long t = blockIdx.x;

    // prologue: DMA tile t into buffer 0
    if (t < ntiles) issue_tile(lds, D1, D2, t, wave, lane);
    __syncthreads();               // drains vmcnt: buffer 0 ready

    int cur = 0;
    while (t < ntiles) {
        long tn = t + tstep;
        if (tn < ntiles)           // issue next tile's DMA BEFORE compute
            issue_tile(lds + (cur ^ 1) * (2 * TILE_FLOATS), D1, D2, tn, wave, lane);

        const float* b = lds + cur * (2 * TILE_FLOATS);
        float m1[6], m2[6], L1[6], L2[6];
        load6(b + tid * 9, m1);
        load6(b + TILE_FLOATS + tid * 9, m2);
        logm3(m1, L1);
        logm3(m2, L2);
        acc += fnorm2_diff(L1, L2);

        __syncthreads();           // waves drain own vmcnt before barrier:
        cur ^= 1;                  // next buffer fully written, old one free
        t = tn;
    }

    // tail (n % TILE pairs): direct loads, only low blocks hit this
    {
        long ti = (long)ntiles * TILE + (long)blockIdx.x * BLOCK + tid;
        if (ti < n) {
            float m1[6], m2[6], L1[6], L2[6];
            load6(D1 + ti * 9, m1);
            load6(D2 + ti * 9, m2);
            logm3(m1, L1);
            logm3(m2, L2);
            acc += fnorm2_diff(L1, L2);
        }
    }

    // wave reduce (wave = 64)
    #pragma unroll
    for (int off = 32; off > 0; off >>= 1)
        acc += __shfl_down(acc, off, 64);
    __shared__ float wsum[BLOCK / 64];
    if (lane == 0) wsum[wave] = acc;
    __syncthreads();
    if (tid == 0) {
        float s = 0.0f;
        #pragma unroll
        for (int j = 0; j < BLOCK / 64; ++j) s += wsum[j];
        partial[blockIdx.x] = s;
    }
}

__global__ void __launch_bounds__(BLOCK)
le_final(const float* __restrict__ partial, int nparts,
         float* __restrict__ out, double invN) {
    double s = 0.0;
    for (int i = threadIdx.x; i < nparts; i += BLOCK)
        s += (double)partial[i];
    #pragma unroll
    for (int off = 32; off > 0; off >>= 1)
        s += __shfl_down(s, off, 64);
    __shared__ double ws[BLOCK / 64];
    if ((threadIdx.x & 63) == 0) ws[threadIdx.x >> 6] = s;
    __syncthreads();
    if (threadIdx.x == 0) {
        double tt = 0.0;
        #pragma unroll
        for (int i = 0; i < BLOCK / 64; ++i) tt += ws[i];
        out[0] = (float)(tt * invN);
    }
}

extern "C" void kernel_launch(void* const* d_in, const int* in_sizes, int n_in,
                              void* d_out, int out_size, void* d_ws, size_t ws_size,
                              hipStream_t stream) {
    const float* D1 = (const float*)d_in[0];
    const float* D2 = (const float*)d_in[1];
    float* out = (float*)d_out;
    float* partial = (float*)d_ws;

    int n = in_sizes[0] / 9;
    int ntiles = n / TILE;          // full tiles; remainder handled as tail

    int grid = 1024;                // 4 blocks/CU residency (LDS-limited), ~7.6 tiles each
    if (ntiles > 0 && grid > ntiles) grid = ntiles;
    int maxblocks = (int)(ws_size / sizeof(float));
    if (maxblocks > 0 && grid > maxblocks) grid = maxblocks;
    if (grid < 1) grid = 1;

    le_partial<<<grid, BLOCK, 0, stream>>>(D1, D2, partial, n, ntiles);
    le_final<<<1, BLOCK, 0, stream>>>(partial, grid, out, 1.0 / (double)n);
}